// Round 11
// baseline (1140.794 us; speedup 1.0000x reference)
//
#include <hip/hip_runtime.h>

namespace {

using v4f    = __attribute__((ext_vector_type(4))) float;
using short8 = __attribute__((ext_vector_type(8))) short;

constexpr int T = 256, GB = 4;

__device__ __forceinline__ float frcp(float x) { return __builtin_amdgcn_rcpf(x); }
__device__ __forceinline__ float sgm(float x) { return frcp(1.f + __expf(-x)); }
__device__ __forceinline__ float ftanh(float x) {
  const float e = __expf(-2.f * x);
  return (1.f - e) * frcp(1.f + e);
}
__device__ __forceinline__ unsigned short f2bf(float f) {
  unsigned x = __float_as_uint(f);
  return (unsigned short)((x + 0x7FFFu + ((x >> 16) & 1u)) >> 16);
}
__device__ __forceinline__ float bf2f(unsigned short s) {
  return __uint_as_float((unsigned)s << 16);
}
__device__ __forceinline__ void cvt8(const float* w, short8& hi, short8& lo) {
#pragma unroll
  for (int j = 0; j < 8; ++j) {
    const unsigned short h = f2bf(w[j]);
    hi[j] = (short)h;
    lo[j] = (short)f2bf(w[j] - bf2f(h));
  }
}

#define MFMA(A, B, C) __builtin_amdgcn_mfma_f32_16x16x32_bf16((A), (B), (C), 0, 0, 0)

__global__ __launch_bounds__(512, 1) void seq2seq_kernel(
    const float* __restrict__ enc_x, const float* __restrict__ dec_x,
    const float* __restrict__ eWih0, const float* __restrict__ eWhh0, const float* __restrict__ eb0,
    const float* __restrict__ eWih1, const float* __restrict__ eWhh1, const float* __restrict__ eb1,
    const float* __restrict__ eWih2, const float* __restrict__ eWhh2, const float* __restrict__ eb2,
    const float* __restrict__ dWih0, const float* __restrict__ dWhh0, const float* __restrict__ db0,
    const float* __restrict__ dWih1, const float* __restrict__ dWhh1, const float* __restrict__ db1,
    const float* __restrict__ dWih2, const float* __restrict__ dWhh2, const float* __restrict__ db2,
    const float* __restrict__ fcW, const float* __restrict__ fcb,
    float* __restrict__ out) {
  // h state: [parity][arr: h0,h1,h2,yp][col][k pad 72]; col g = hi(batch g), g+8 = lo.
  __shared__ __align__(16) unsigned short hb[2][4][16][72];  // 18.4 KB
  __shared__ float xs[2][GB][T];       // 8 KB
  __shared__ float biasq[6][64][4];    // 6 KB  bias swizzled [row][unit][gate]
  __shared__ float fcring[32][8][5];   // 5 KB  fc partials ring

  const int tid = threadIdx.x;
  const int w = tid >> 6, l = tid & 63;
  const int col = l & 15;   // B col / A row-in-tile
  const int q = l >> 4;     // k-subgroup; C rows q*4..q*4+3
  const int b0 = blockIdx.x * GB;

  // ---- stage x; swizzled biases; zero h state (both parities) ----
  for (int i = tid; i < GB * T; i += 512) {
    ((float*)xs[0])[i] = enc_x[b0 * T + i];
    ((float*)xs[1])[i] = dec_x[b0 * T + i];
  }
  if (tid < 256) {
    const int u_ = tid & 63, r_ = tid >> 6;
    biasq[0][u_][r_] = eb0[r_ * 64 + u_];
    biasq[1][u_][r_] = eb1[r_ * 64 + u_];
    biasq[2][u_][r_] = eb2[r_ * 64 + u_];
    biasq[3][u_][r_] = db0[r_ * 64 + u_];
    biasq[4][u_][r_] = db1[r_ * 64 + u_];
    biasq[5][u_][r_] = db2[r_ * 64 + u_];
  }
  for (int i = tid; i < (int)(sizeof(hb) / 4); i += 512) ((unsigned*)hb)[i] = 0u;

  float cst[3][2] = {{0.f, 0.f}, {0.f, 0.f}, {0.f, 0.f}};  // cell state, in-lane
  float fcw_[2] = {0.f, 0.f};
  const float fcb0 = fcb[0];

  // ---- resident A-frags, gate-interleaved: vr(tile,m) = (m&3)*64 + tile*4 + (m>>2) ----
  short8 Ah[6][2][2], Al[6][2][2];
  v4f xwc[2];

#define BUILD(S, W)                                                           \
  _Pragma("unroll") for (int mt = 0; mt < 2; ++mt)                            \
  _Pragma("unroll") for (int kc = 0; kc < 2; ++kc) {                          \
    const int vr = (col & 3) * 64 + (2 * w + mt) * 4 + (col >> 2);            \
    cvt8((W) + vr * 64 + kc * 32 + q * 8, Ah[S][mt][kc], Al[S][mt][kc]);      \
  }
#define BUILDU(S, W)                                                          \
  _Pragma("unroll") for (int mt = 0; mt < 2; ++mt)                            \
  _Pragma("unroll") for (int kc = 0; kc < 2; ++kc) {                          \
    const int vr = (col & 3) * 64 + (2 * w + mt) * 4 + (col >> 2);            \
    float tw[8];                                                              \
    const float* p = (W) + vr * 65 + 1 + kc * 32 + q * 8;                     \
    _Pragma("unroll") for (int j = 0; j < 8; ++j) tw[j] = p[j];               \
    cvt8(tw, Ah[S][mt][kc], Al[S][mt][kc]);                                   \
  }

  BUILD(0, eWhh0) BUILD(1, eWih1) BUILD(2, eWhh1) BUILD(3, eWih2) BUILD(4, eWhh2)
#pragma unroll
  for (int mt = 0; mt < 2; ++mt) {
    const int U = (2 * w + mt) * 4 + q;
    xwc[mt] = (v4f){eWih0[U], eWih0[64 + U], eWih0[128 + U], eWih0[192 + U]};
  }

  __syncthreads();

#define ACLR                                                                  \
  v4f acc[2];                                                                 \
  acc[0] = (v4f){0.f, 0.f, 0.f, 0.f};                                         \
  acc[1] = (v4f){0.f, 0.f, 0.f, 0.f};

#define LDB2N(N, AR, RP)                                                      \
  const short8 b0##N = *(const short8*)&hb[RP][AR][col][q * 8];               \
  const short8 b1##N = *(const short8*)&hb[RP][AR][col][32 + q * 8];

#define DUO(S, MT, KC, B)                                                     \
  acc[MT] = MFMA(Ah[S][MT][KC], (B), acc[MT]);                                \
  acc[MT] = MFMA(Al[S][MT][KC], (B), acc[MT]);

#define MATN(S, N)                                                            \
  DUO(S, 0, 0, b0##N) DUO(S, 1, 0, b0##N)                                     \
  DUO(S, 0, 1, b1##N) DUO(S, 1, 1, b1##N)

#define CMB                                                                   \
  _Pragma("unroll") for (int mt = 0; mt < 2; ++mt)                            \
  _Pragma("unroll") for (int r = 0; r < 4; ++r)                               \
      acc[mt][r] += __shfl_xor(acc[mt][r], 8, 64);

// In-lane update: acc[mt][r] = gate r of unit U=(2w+mt)*4+q (after CMB).
// Lanes col<4 write hi at [col][U]; lanes 8<=col<12 write lo at [col][U].
#define GUPD(L, BROW, XF, XSEL, YPDUP, DOFC, TP)                              \
  {                                                                           \
    float xv = 0.f;                                                           \
    if (XF) xv = xs[XSEL][col & 3][t];                                        \
    float prl = 0.f; (void)prl;                                               \
    const bool whi = (col < 4), wlo = (col >= 8 && col < 12);                 \
    _Pragma("unroll") for (int mt = 0; mt < 2; ++mt) {                        \
      const int U = (2 * w + mt) * 4 + q;                                     \
      v4f z = acc[mt] + *(const v4f*)&biasq[BROW][U][0];                      \
      if (XF) z += xwc[mt] * xv;                                              \
      const float ii = sgm(z[0]), ff = sgm(z[1]);                             \
      const float gg = ftanh(z[2]), oo = sgm(z[3]);                           \
      const float cn = ff * cst[L][mt] + ii * gg;                             \
      cst[L][mt] = cn;                                                        \
      const float hn = oo * ftanh(cn);                                        \
      const unsigned short hh = f2bf(hn);                                     \
      const unsigned short hl2 = f2bf(hn - bf2f(hh));                         \
      const unsigned short val = whi ? hh : hl2;                              \
      if (whi || wlo) {                                                       \
        hb[TP][L][col][U] = val;                                              \
        if (YPDUP) hb[TP][3][col][U] = val;                                   \
      }                                                                       \
      if (DOFC) prl += fcw_[mt] * hn;                                         \
    }                                                                         \
    if (DOFC) {                                                               \
      prl += __shfl_xor(prl, 16, 64);                                         \
      prl += __shfl_xor(prl, 32, 64);                                         \
      if (q == 0 && col < 4) fcring[t & 31][w][col] = prl;                    \
    }                                                                         \
  }                                                                           \
  __syncthreads();

#define ENCSTEP(TP)                                                           \
  { ACLR LDB2N(a, 0, (TP) ^ 1) MATN(0, a) CMB GUPD(0, 0, 1, 0, 0, 0, TP) }    \
  { ACLR LDB2N(a, 0, TP) LDB2N(b, 1, (TP) ^ 1) MATN(1, a) MATN(2, b) CMB      \
    GUPD(1, 1, 0, 0, 0, 0, TP) }                                              \
  { ACLR LDB2N(a, 1, TP) LDB2N(b, 2, (TP) ^ 1) MATN(3, a) MATN(4, b) CMB      \
    GUPD(2, 2, 0, 0, 0, 0, TP) }

#define DECSTEP(TP)                                                           \
  { ACLR LDB2N(a, 3, (TP) ^ 1) LDB2N(b, 0, (TP) ^ 1) MATN(5, a) MATN(0, b)    \
    CMB GUPD(0, 3, 1, 1, 0, 0, TP) }                                          \
  { ACLR LDB2N(a, 0, TP) LDB2N(b, 1, (TP) ^ 1) MATN(1, a) MATN(2, b) CMB      \
    GUPD(1, 4, 0, 0, 0, 0, TP) }                                              \
  { ACLR LDB2N(a, 1, TP) LDB2N(b, 2, (TP) ^ 1) MATN(3, a) MATN(4, b) CMB      \
    GUPD(2, 5, 0, 0, 1, 1, TP) }

  // ---------------- Encoder ----------------
#pragma clang loop unroll(disable)
  for (int t2 = 0; t2 < T; t2 += 2) {
    { const int t = t2;     ENCSTEP(0) }
    { const int t = t2 + 1; ENCSTEP(1) }
  }

  // ---- decoder weights (rebuild; slot 5 = y-columns of dWih0) ----
  BUILD(0, dWhh0) BUILD(1, dWih1) BUILD(2, dWhh1) BUILD(3, dWih2) BUILD(4, dWhh2)
  BUILDU(5, dWih0)
#pragma unroll
  for (int mt = 0; mt < 2; ++mt) {
    const int U = (2 * w + mt) * 4 + q;
    xwc[mt] = (v4f){dWih0[U * 65], dWih0[(64 + U) * 65],
                    dWih0[(128 + U) * 65], dWih0[(192 + U) * 65]};
    fcw_[mt] = fcW[U];
  }

  // ---------------- Decoder ----------------
#pragma clang loop unroll(disable)
  for (int t2 = 0; t2 < T; t2 += 2) {
    {
      const int t = t2;
      if (t > 0 && (t & 31) == 0 && tid < 128) {  // flush preds t-32..t-1
        const int ti = tid >> 2, c4 = tid & 3;
        float s = fcb0;
#pragma unroll
        for (int ww = 0; ww < 8; ++ww) s += fcring[ti][ww][c4];
        out[(b0 + c4) * T + (t - 32) + ti] = s;
      }
      DECSTEP(0)
    }
    { const int t = t2 + 1; DECSTEP(1) }
  }
  // final flush: t = 224..255
  if (tid < 128) {
    const int ti = tid >> 2, c4 = tid & 3;
    float s = fcb0;
#pragma unroll
    for (int ww = 0; ww < 8; ++ww) s += fcring[ti][ww][c4];
    out[(b0 + c4) * T + 224 + ti] = s;
  }

#undef DECSTEP
#undef ENCSTEP
#undef GUPD
#undef CMB
#undef MATN
#undef DUO
#undef LDB2N
#undef ACLR
#undef BUILDU
#undef BUILD
}

}  // namespace

extern "C" void kernel_launch(void* const* d_in, const int* in_sizes, int n_in,
                              void* d_out, int out_size, void* d_ws, size_t ws_size,
                              hipStream_t stream) {
  const float* enc_x = (const float*)d_in[0];
  const float* dec_x = (const float*)d_in[1];
  const float* eWih0 = (const float*)d_in[2];
  const float* eWhh0 = (const float*)d_in[3];
  const float* eb0   = (const float*)d_in[4];
  const float* eWih1 = (const float*)d_in[5];
  const float* eWhh1 = (const float*)d_in[6];
  const float* eb1   = (const float*)d_in[7];
  const float* eWih2 = (const float*)d_in[8];
  const float* eWhh2 = (const float*)d_in[9];
  const float* eb2   = (const float*)d_in[10];
  const float* dWih0 = (const float*)d_in[11];
  const float* dWhh0 = (const float*)d_in[12];
  const float* db0   = (const float*)d_in[13];
  const float* dWih1 = (const float*)d_in[14];
  const float* dWhh1 = (const float*)d_in[15];
  const float* db1   = (const float*)d_in[16];
  const float* dWih2 = (const float*)d_in[17];
  const float* dWhh2 = (const float*)d_in[18];
  const float* db2   = (const float*)d_in[19];
  const float* fcW   = (const float*)d_in[20];
  const float* fcb   = (const float*)d_in[21];
  float* out = (float*)d_out;

  seq2seq_kernel<<<dim3(256), dim3(512), 0, stream>>>(
      enc_x, dec_x, eWih0, eWhh0, eb0, eWih1, eWhh1, eb1, eWih2, eWhh2, eb2,
      dWih0, dWhh0, db0, dWih1, dWhh1, db1, dWih2, dWhh2, db2, fcW, fcb, out);
}

// Round 12
// 1132.082 us; speedup vs baseline: 1.0077x; 1.0077x over previous
//
#include <hip/hip_runtime.h>

namespace {

using v4f    = __attribute__((ext_vector_type(4))) float;
using short8 = __attribute__((ext_vector_type(8))) short;

constexpr int T = 256, GB = 4;

__device__ __forceinline__ float frcp(float x) { return __builtin_amdgcn_rcpf(x); }
__device__ __forceinline__ float sgm(float x) { return frcp(1.f + __expf(-x)); }
__device__ __forceinline__ float ftanh(float x) {
  const float e = __expf(-2.f * x);
  return (1.f - e) * frcp(1.f + e);
}
__device__ __forceinline__ unsigned short f2bf(float f) {
  unsigned x = __float_as_uint(f);
  return (unsigned short)((x + 0x7FFFu + ((x >> 16) & 1u)) >> 16);
}
__device__ __forceinline__ float bf2f(unsigned short s) {
  return __uint_as_float((unsigned)s << 16);
}
__device__ __forceinline__ void cvt8(const float* w, short8& hi, short8& lo) {
#pragma unroll
  for (int j = 0; j < 8; ++j) {
    const unsigned short h = f2bf(w[j]);
    hi[j] = (short)h;
    lo[j] = (short)f2bf(w[j] - bf2f(h));
  }
}

#define MFMA(A, B, C) __builtin_amdgcn_mfma_f32_16x16x32_bf16((A), (B), (C), 0, 0, 0)

__global__ __launch_bounds__(512, 1) void seq2seq_kernel(
    const float* __restrict__ enc_x, const float* __restrict__ dec_x,
    const float* __restrict__ eWih0, const float* __restrict__ eWhh0, const float* __restrict__ eb0,
    const float* __restrict__ eWih1, const float* __restrict__ eWhh1, const float* __restrict__ eb1,
    const float* __restrict__ eWih2, const float* __restrict__ eWhh2, const float* __restrict__ eb2,
    const float* __restrict__ dWih0, const float* __restrict__ dWhh0, const float* __restrict__ db0,
    const float* __restrict__ dWih1, const float* __restrict__ dWhh1, const float* __restrict__ db1,
    const float* __restrict__ dWih2, const float* __restrict__ dWhh2, const float* __restrict__ db2,
    const float* __restrict__ fcW, const float* __restrict__ fcb,
    float* __restrict__ out) {
  // h state: [parity][arr: h0,h1,h2,yp][col][k pad 72]; col g = hi(batch g), g+8 = lo.
  __shared__ __align__(16) unsigned short hb[2][4][16][72];  // 18.4 KB
  __shared__ float xs[2][GB][T];       // 8 KB
  __shared__ float biasq[6][64][4];    // 6 KB  bias swizzled [row][unit][gate]
  __shared__ float fcring[32][8][5];   // 5 KB  fc partials ring

  const int tid = threadIdx.x;
  const int w = tid >> 6, l = tid & 63;
  const int col = l & 15;   // B col / A row-in-tile
  const int q = l >> 4;     // k-subgroup; C rows q*4..q*4+3
  const int b0 = blockIdx.x * GB;

  // ---- stage x; swizzled biases; zero h state (both parities) ----
  for (int i = tid; i < GB * T; i += 512) {
    ((float*)xs[0])[i] = enc_x[b0 * T + i];
    ((float*)xs[1])[i] = dec_x[b0 * T + i];
  }
  if (tid < 256) {
    const int u_ = tid & 63, r_ = tid >> 6;
    biasq[0][u_][r_] = eb0[r_ * 64 + u_];
    biasq[1][u_][r_] = eb1[r_ * 64 + u_];
    biasq[2][u_][r_] = eb2[r_ * 64 + u_];
    biasq[3][u_][r_] = db0[r_ * 64 + u_];
    biasq[4][u_][r_] = db1[r_ * 64 + u_];
    biasq[5][u_][r_] = db2[r_ * 64 + u_];
  }
  for (int i = tid; i < (int)(sizeof(hb) / 4); i += 512) ((unsigned*)hb)[i] = 0u;

  float cst[3][2] = {{0.f, 0.f}, {0.f, 0.f}, {0.f, 0.f}};  // cell state, in-lane
  float fcw_[2] = {0.f, 0.f};
  const float fcb0 = fcb[0];

  // ---- resident A-frags, gate-interleaved: vr(tile,m) = (m&3)*64 + tile*4 + (m>>2) ----
  short8 Ah[6][2][2], Al[6][2][2];
  v4f xwc[2];

#define BUILD(S, W)                                                           \
  _Pragma("unroll") for (int mt = 0; mt < 2; ++mt)                            \
  _Pragma("unroll") for (int kc = 0; kc < 2; ++kc) {                          \
    const int vr = (col & 3) * 64 + (2 * w + mt) * 4 + (col >> 2);            \
    cvt8((W) + vr * 64 + kc * 32 + q * 8, Ah[S][mt][kc], Al[S][mt][kc]);      \
  }
#define BUILDU(S, W)                                                          \
  _Pragma("unroll") for (int mt = 0; mt < 2; ++mt)                            \
  _Pragma("unroll") for (int kc = 0; kc < 2; ++kc) {                          \
    const int vr = (col & 3) * 64 + (2 * w + mt) * 4 + (col >> 2);            \
    float tw[8];                                                              \
    const float* p = (W) + vr * 65 + 1 + kc * 32 + q * 8;                     \
    _Pragma("unroll") for (int j = 0; j < 8; ++j) tw[j] = p[j];               \
    cvt8(tw, Ah[S][mt][kc], Al[S][mt][kc]);                                   \
  }

  BUILD(0, eWhh0) BUILD(1, eWih1) BUILD(2, eWhh1) BUILD(3, eWih2) BUILD(4, eWhh2)
#pragma unroll
  for (int mt = 0; mt < 2; ++mt) {
    const int U = (2 * w + mt) * 4 + q;
    xwc[mt] = (v4f){eWih0[U], eWih0[64 + U], eWih0[128 + U], eWih0[192 + U]};
  }

  __syncthreads();

#define ZV4 (v4f){0.f, 0.f, 0.f, 0.f}

#define LDBP(NAME, AR, PP)                                                    \
  const short8 NAME##0 = *(const short8*)&hb[(PP)][AR][col][q * 8];           \
  const short8 NAME##1 = *(const short8*)&hb[(PP)][AR][col][32 + q * 8];

#define DUO2(ACC, S, MT, KC, B)                                               \
  ACC[MT] = MFMA(Ah[S][MT][KC], (B), ACC[MT]);                                \
  ACC[MT] = MFMA(Al[S][MT][KC], (B), ACC[MT]);

#define MATX(ACC, S, N)                                                       \
  DUO2(ACC, S, 0, 0, N##0) DUO2(ACC, S, 1, 0, N##0)                           \
  DUO2(ACC, S, 0, 1, N##1) DUO2(ACC, S, 1, 1, N##1)

#define CMBX(ACC)                                                             \
  _Pragma("unroll") for (int mt = 0; mt < 2; ++mt)                            \
  _Pragma("unroll") for (int r = 0; r < 4; ++r)                               \
      ACC[mt][r] += __shfl_xor(ACC[mt][r], 8, 64);

// In-lane gate update (no barrier inside). ACC[mt][r] = gate r of unit
// U=(2w+mt)*4+q. Lanes col<4 write hi at [col][U]; 8<=col<12 write lo.
#define GUPDX(ACC, L, BROW, XF, XSEL, TT, YPDUP, DOFC, TP)                    \
  {                                                                           \
    float xv = 0.f;                                                           \
    if (XF) xv = xs[XSEL][col & 3][TT];                                       \
    float prl = 0.f; (void)prl;                                               \
    const bool whi = (col < 4), wlo = (col >= 8 && col < 12);                 \
    _Pragma("unroll") for (int mt = 0; mt < 2; ++mt) {                        \
      const int U = (2 * w + mt) * 4 + q;                                     \
      v4f z = ACC[mt] + *(const v4f*)&biasq[BROW][U][0];                      \
      if (XF) z += xwc[mt] * xv;                                              \
      const float ii = sgm(z[0]), ff = sgm(z[1]);                             \
      const float gg = ftanh(z[2]), oo = sgm(z[3]);                           \
      const float cn = ff * cst[L][mt] + ii * gg;                             \
      cst[L][mt] = cn;                                                        \
      const float hn = oo * ftanh(cn);                                        \
      const unsigned short hh = f2bf(hn);                                     \
      const unsigned short hl2 = f2bf(hn - bf2f(hh));                         \
      const unsigned short val = whi ? hh : hl2;                              \
      if (whi || wlo) {                                                       \
        hb[TP][L][col][U] = val;                                              \
        if (YPDUP) hb[TP][3][col][U] = val;                                   \
      }                                                                       \
      if (DOFC) prl += fcw_[mt] * hn;                                         \
    }                                                                         \
    if (DOFC) {                                                               \
      prl += __shfl_xor(prl, 16, 64);                                         \
      prl += __shfl_xor(prl, 32, 64);                                         \
      if (q == 0 && col < 4) fcring[(TT) & 31][w][col] = prl;                 \
    }                                                                         \
  }

  // ---------------- Encoder: diagonal-pipelined supersteps ----------------
  // Superstep s computes L0@t=s, L1@t=s-1, L2@t=s-2. All reads from parity
  // Pn = (s-1)&1, all writes to P = s&1. ONE barrier per superstep.
#pragma clang loop unroll(disable)
  for (int s = 0; s < T + 2; ++s) {
    const int P = s & 1, Pn = P ^ 1;
    LDBP(f0, 0, Pn) LDBP(f1, 1, Pn) LDBP(f2, 2, Pn)
    v4f a0c[2], a1c[2], a2c[2];
    a0c[0] = ZV4; a0c[1] = ZV4;
    a1c[0] = ZV4; a1c[1] = ZV4;
    a2c[0] = ZV4; a2c[1] = ZV4;
    MATX(a0c, 0, f0)
    MATX(a1c, 1, f0) MATX(a1c, 2, f1)
    MATX(a2c, 3, f1) MATX(a2c, 4, f2)
    CMBX(a0c) CMBX(a1c) CMBX(a2c)
    if (s >= 2 && s < T) {  // fast path: all three layers active (254/258)
      GUPDX(a0c, 0, 0, 1, 0, s, 0, 0, P)
      GUPDX(a1c, 1, 1, 0, 0, 0, 0, 0, P)
      GUPDX(a2c, 2, 2, 0, 0, 0, 0, 0, P)
    } else {
      if (s < T)            { GUPDX(a0c, 0, 0, 1, 0, s, 0, 0, P) }
      if (s >= 1 && s <= T) { GUPDX(a1c, 1, 1, 0, 0, 0, 0, 0, P) }
      if (s >= 2)           { GUPDX(a2c, 2, 2, 0, 0, 0, 0, 0, P) }
    }
    __syncthreads();
  }

  // Parity fixup: enc-final h0[T-1] landed at parity 1 (s=255), h2[T-1] at
  // parity 1 (s=257) -- where decoder t=0 expects them. h1[T-1] landed at
  // parity 0 (s=256): copy to parity 1.
  {
    unsigned* dst = (unsigned*)&hb[1][1][0][0];
    const unsigned* src = (const unsigned*)&hb[0][1][0][0];
    for (int i = tid; i < 16 * 72 / 2; i += 512) dst[i] = src[i];
  }
  __syncthreads();

  // ---- decoder weights (rebuild; slot 5 = y-columns of dWih0) ----
  BUILD(0, dWhh0) BUILD(1, dWih1) BUILD(2, dWhh1) BUILD(3, dWih2) BUILD(4, dWhh2)
  BUILDU(5, dWih0)
#pragma unroll
  for (int mt = 0; mt < 2; ++mt) {
    const int U = (2 * w + mt) * 4 + q;
    xwc[mt] = (v4f){dWih0[U * 65], dWih0[(64 + U) * 65],
                    dWih0[(128 + U) * 65], dWih0[(192 + U) * 65]};
    fcw_[mt] = fcW[U];
  }

#define ACLR2                                                                 \
  v4f acc[2];                                                                 \
  acc[0] = ZV4; acc[1] = ZV4;

#define DSTEP(TP)                                                             \
  { ACLR2 LDBP(ya, 3, (TP) ^ 1) LDBP(n0, 0, (TP) ^ 1)                         \
    MATX(acc, 5, ya) MATX(acc, 0, n0) CMBX(acc)                               \
    GUPDX(acc, 0, 3, 1, 1, t, 0, 0, TP) }                                     \
  __syncthreads();                                                            \
  { ACLR2 LDBP(n1, 0, TP) LDBP(n2, 1, (TP) ^ 1)                               \
    MATX(acc, 1, n1) MATX(acc, 2, n2) CMBX(acc)                               \
    GUPDX(acc, 1, 4, 0, 0, t, 0, 0, TP) }                                     \
  __syncthreads();                                                            \
  { ACLR2 LDBP(n3, 1, TP) LDBP(n4, 2, (TP) ^ 1)                               \
    MATX(acc, 3, n3) MATX(acc, 4, n4) CMBX(acc)                               \
    GUPDX(acc, 2, 5, 0, 0, t, 1, 1, TP) }                                     \
  __syncthreads();

  // ---------------- Decoder (3 serial phases/t; y-feedback) ----------------
#pragma clang loop unroll(disable)
  for (int t2 = 0; t2 < T; t2 += 2) {
    {
      const int t = t2;
      if (t > 0 && (t & 31) == 0 && tid < 128) {  // flush preds t-32..t-1
        const int ti = tid >> 2, c4 = tid & 3;
        float s = fcb0;
#pragma unroll
        for (int ww = 0; ww < 8; ++ww) s += fcring[ti][ww][c4];
        out[(b0 + c4) * T + (t - 32) + ti] = s;
      }
      DSTEP(0)
    }
    { const int t = t2 + 1; DSTEP(1) }
  }
  // final flush: t = 224..255
  if (tid < 128) {
    const int ti = tid >> 2, c4 = tid & 3;
    float s = fcb0;
#pragma unroll
    for (int ww = 0; ww < 8; ++ww) s += fcring[ti][ww][c4];
    out[(b0 + c4) * T + 224 + ti] = s;
  }

#undef DSTEP
#undef ACLR2
#undef GUPDX
#undef CMBX
#undef MATX
#undef DUO2
#undef LDBP
#undef ZV4
#undef BUILDU
#undef BUILD
}

}  // namespace

extern "C" void kernel_launch(void* const* d_in, const int* in_sizes, int n_in,
                              void* d_out, int out_size, void* d_ws, size_t ws_size,
                              hipStream_t stream) {
  const float* enc_x = (const float*)d_in[0];
  const float* dec_x = (const float*)d_in[1];
  const float* eWih0 = (const float*)d_in[2];
  const float* eWhh0 = (const float*)d_in[3];
  const float* eb0   = (const float*)d_in[4];
  const float* eWih1 = (const float*)d_in[5];
  const float* eWhh1 = (const float*)d_in[6];
  const float* eb1   = (const float*)d_in[7];
  const float* eWih2 = (const float*)d_in[8];
  const float* eWhh2 = (const float*)d_in[9];
  const float* eb2   = (const float*)d_in[10];
  const float* dWih0 = (const float*)d_in[11];
  const float* dWhh0 = (const float*)d_in[12];
  const float* db0   = (const float*)d_in[13];
  const float* dWih1 = (const float*)d_in[14];
  const float* dWhh1 = (const float*)d_in[15];
  const float* db1   = (const float*)d_in[16];
  const float* dWih2 = (const float*)d_in[17];
  const float* dWhh2 = (const float*)d_in[18];
  const float* db2   = (const float*)d_in[19];
  const float* fcW   = (const float*)d_in[20];
  const float* fcb   = (const float*)d_in[21];
  float* out = (float*)d_out;

  seq2seq_kernel<<<dim3(256), dim3(512), 0, stream>>>(
      enc_x, dec_x, eWih0, eWhh0, eb0, eWih1, eWhh1, eb1, eWih2, eWhh2, eb2,
      dWih0, dWhh0, db0, dWih1, dWhh1, db1, dWih2, dWhh2, db2, fcW, fcb, out);
}

// Round 13
// 804.897 us; speedup vs baseline: 1.4173x; 1.4065x over previous
//
#include <hip/hip_runtime.h>

namespace {

using v4f    = __attribute__((ext_vector_type(4))) float;
using short8 = __attribute__((ext_vector_type(8))) short;

constexpr int T = 256, GB = 4;

__device__ __forceinline__ float frcp(float x) { return __builtin_amdgcn_rcpf(x); }
__device__ __forceinline__ float sgm(float x) { return frcp(1.f + __expf(-x)); }
__device__ __forceinline__ float ftanh(float x) {
  const float e = __expf(-2.f * x);
  return (1.f - e) * frcp(1.f + e);
}
__device__ __forceinline__ unsigned short f2bf(float f) {
  unsigned x = __float_as_uint(f);
  return (unsigned short)((x + 0x7FFFu + ((x >> 16) & 1u)) >> 16);
}
__device__ __forceinline__ float bf2f(unsigned short s) {
  return __uint_as_float((unsigned)s << 16);
}
__device__ __forceinline__ void cvt8(const float* w, short8& hi, short8& lo) {
#pragma unroll
  for (int j = 0; j < 8; ++j) {
    const unsigned short h = f2bf(w[j]);
    hi[j] = (short)h;
    lo[j] = (short)f2bf(w[j] - bf2f(h));
  }
}

#define MFMA(A, B, C) __builtin_amdgcn_mfma_f32_16x16x32_bf16((A), (B), (C), 0, 0, 0)

__global__ __launch_bounds__(512, 1) void seq2seq_kernel(
    const float* __restrict__ enc_x, const float* __restrict__ dec_x,
    const float* __restrict__ eWih0, const float* __restrict__ eWhh0, const float* __restrict__ eb0,
    const float* __restrict__ eWih1, const float* __restrict__ eWhh1, const float* __restrict__ eb1,
    const float* __restrict__ eWih2, const float* __restrict__ eWhh2, const float* __restrict__ eb2,
    const float* __restrict__ dWih0, const float* __restrict__ dWhh0, const float* __restrict__ db0,
    const float* __restrict__ dWih1, const float* __restrict__ dWhh1, const float* __restrict__ db1,
    const float* __restrict__ dWih2, const float* __restrict__ dWhh2, const float* __restrict__ db2,
    const float* __restrict__ fcW, const float* __restrict__ fcb,
    float* __restrict__ out) {
  // h state: [parity][arr: h0,h1,h2,yp][col][k pad 72]; col g = hi(batch g), g+8 = lo.
  __shared__ __align__(16) unsigned short hb[2][4][16][72];  // 18.4 KB
  __shared__ float xs[2][GB][T];       // 8 KB
  __shared__ float biasq[6][64][4];    // 6 KB  bias swizzled [row][unit][gate]
  __shared__ float fcring[32][8][5];   // 5 KB  fc partials ring

  const int tid = threadIdx.x;
  const int w = tid >> 6, l = tid & 63;
  const int col = l & 15;   // B col / A row-in-tile
  const int q = l >> 4;     // k-subgroup; C rows q*4..q*4+3
  const int b0 = blockIdx.x * GB;

  // Despecialization constants: each lane owns ONE gate-set.
  const bool hiL = (col < 8);               // lanes col<8 -> mt=0, col>=8 -> mt=1
  const bool useful = ((col & 7) < 4);      // cols 4-7, 12-15 are zero padding
  const int hirow = col & 7;                // hi-store row (0..3 on useful lanes)
  const int U_sel = (2 * w + (hiL ? 0 : 1)) * 4 + q;  // this lane's unit

  // ---- stage x; swizzled biases; zero h state (both parities) ----
  for (int i = tid; i < GB * T; i += 512) {
    ((float*)xs[0])[i] = enc_x[b0 * T + i];
    ((float*)xs[1])[i] = dec_x[b0 * T + i];
  }
  if (tid < 256) {
    const int u_ = tid & 63, r_ = tid >> 6;
    biasq[0][u_][r_] = eb0[r_ * 64 + u_];
    biasq[1][u_][r_] = eb1[r_ * 64 + u_];
    biasq[2][u_][r_] = eb2[r_ * 64 + u_];
    biasq[3][u_][r_] = db0[r_ * 64 + u_];
    biasq[4][u_][r_] = db1[r_ * 64 + u_];
    biasq[5][u_][r_] = db2[r_ * 64 + u_];
  }
  for (int i = tid; i < (int)(sizeof(hb) / 4); i += 512) ((unsigned*)hb)[i] = 0u;

  float cst[3] = {0.f, 0.f, 0.f};  // cell state: this lane's (unit U_sel, batch col&3)
  const float fcb0 = fcb[0];

  // ---- resident A-frags, gate-interleaved: vr(tile,m) = (m&3)*64 + tile*4 + (m>>2) ----
  short8 Ah[6][2][2], Al[6][2][2];
  v4f xwc_sel;
  float fcw_sel = 0.f;

#define BUILD(S, W)                                                           \
  _Pragma("unroll") for (int mt = 0; mt < 2; ++mt)                            \
  _Pragma("unroll") for (int kc = 0; kc < 2; ++kc) {                          \
    const int vr = (col & 3) * 64 + (2 * w + mt) * 4 + (col >> 2);            \
    cvt8((W) + vr * 64 + kc * 32 + q * 8, Ah[S][mt][kc], Al[S][mt][kc]);      \
  }
#define BUILDU(S, W)                                                          \
  _Pragma("unroll") for (int mt = 0; mt < 2; ++mt)                            \
  _Pragma("unroll") for (int kc = 0; kc < 2; ++kc) {                          \
    const int vr = (col & 3) * 64 + (2 * w + mt) * 4 + (col >> 2);            \
    float tw[8];                                                              \
    const float* p = (W) + vr * 65 + 1 + kc * 32 + q * 8;                     \
    _Pragma("unroll") for (int j = 0; j < 8; ++j) tw[j] = p[j];               \
    cvt8(tw, Ah[S][mt][kc], Al[S][mt][kc]);                                   \
  }

  BUILD(0, eWhh0) BUILD(1, eWih1) BUILD(2, eWhh1) BUILD(3, eWih2) BUILD(4, eWhh2)
  xwc_sel = (v4f){eWih0[U_sel], eWih0[64 + U_sel], eWih0[128 + U_sel], eWih0[192 + U_sel]};

  __syncthreads();

#define ZV4 (v4f){0.f, 0.f, 0.f, 0.f}

#define LDBP(NAME, AR, PP)                                                    \
  const short8 NAME##0 = *(const short8*)&hb[(PP)][AR][col][q * 8];           \
  const short8 NAME##1 = *(const short8*)&hb[(PP)][AR][col][32 + q * 8];

#define DUO2(ACC, S, MT, KC, B)                                               \
  ACC[MT] = MFMA(Ah[S][MT][KC], (B), ACC[MT]);                                \
  ACC[MT] = MFMA(Al[S][MT][KC], (B), ACC[MT]);

#define MATX(ACC, S, N)                                                       \
  DUO2(ACC, S, 0, 0, N##0) DUO2(ACC, S, 1, 0, N##0)                           \
  DUO2(ACC, S, 0, 1, N##1) DUO2(ACC, S, 1, 1, N##1)

// Despecialized gate update: select own mt, exchange the partner term via
// one shfl_xor(8), then ONE gate-set of transcendentals per lane.
#define GUPDX(ACC, L, BROW, XF, XSEL, TT, YPDUP, DOFC, TP)                    \
  {                                                                           \
    const v4f zsel = hiL ? ACC[0] : ACC[1];                                   \
    const v4f wsel = hiL ? ACC[1] : ACC[0];                                   \
    v4f z;                                                                    \
    _Pragma("unroll") for (int r = 0; r < 4; ++r)                             \
        z[r] = zsel[r] + __shfl_xor(wsel[r], 8, 64);                          \
    z += *(const v4f*)&biasq[BROW][U_sel][0];                                 \
    if (XF) {                                                                 \
      const float xv = xs[XSEL][col & 3][TT];                                 \
      z += xwc_sel * xv;                                                      \
    }                                                                         \
    const float ii = sgm(z[0]), ff = sgm(z[1]);                               \
    const float gg = ftanh(z[2]), oo = sgm(z[3]);                             \
    const float cn = ff * cst[L] + ii * gg;                                   \
    cst[L] = cn;                                                              \
    const float hn = oo * ftanh(cn);                                          \
    const unsigned short hh = f2bf(hn);                                       \
    const unsigned short hl2 = f2bf(hn - bf2f(hh));                           \
    if (useful) {                                                             \
      hb[TP][L][hirow][U_sel] = hh;                                           \
      hb[TP][L][hirow + 8][U_sel] = hl2;                                      \
      if (YPDUP) {                                                            \
        hb[TP][3][hirow][U_sel] = hh;                                         \
        hb[TP][3][hirow + 8][U_sel] = hl2;                                    \
      }                                                                       \
    }                                                                         \
    if (DOFC) {                                                               \
      float prl = useful ? fcw_sel * hn : 0.f;                                \
      prl += __shfl_xor(prl, 16, 64);                                         \
      prl += __shfl_xor(prl, 32, 64);                                         \
      prl += __shfl_xor(prl, 8, 64);                                          \
      if (q == 0 && col < 4) fcring[(TT) & 31][w][col] = prl;                 \
    }                                                                         \
  }

  // ---------------- Encoder: diagonal-pipelined supersteps ----------------
  // Superstep s computes L0@t=s, L1@t=s-1, L2@t=s-2. Reads parity (s-1)&1,
  // writes parity s&1. ONE barrier per superstep.
#pragma clang loop unroll(disable)
  for (int s = 0; s < T + 2; ++s) {
    const int P = s & 1, Pn = P ^ 1;
    LDBP(f0, 0, Pn) LDBP(f1, 1, Pn) LDBP(f2, 2, Pn)
    v4f a0c[2], a1c[2], a2c[2];
    a0c[0] = ZV4; a0c[1] = ZV4;
    a1c[0] = ZV4; a1c[1] = ZV4;
    a2c[0] = ZV4; a2c[1] = ZV4;
    MATX(a0c, 0, f0)
    MATX(a1c, 1, f0) MATX(a1c, 2, f1)
    MATX(a2c, 3, f1) MATX(a2c, 4, f2)
    if (s >= 2 && s < T) {  // fast path: all three layers active
      GUPDX(a0c, 0, 0, 1, 0, s, 0, 0, P)
      GUPDX(a1c, 1, 1, 0, 0, 0, 0, 0, P)
      GUPDX(a2c, 2, 2, 0, 0, 0, 0, 0, P)
    } else {
      if (s < T)            { GUPDX(a0c, 0, 0, 1, 0, s, 0, 0, P) }
      if (s >= 1 && s <= T) { GUPDX(a1c, 1, 1, 0, 0, 0, 0, 0, P) }
      if (s >= 2)           { GUPDX(a2c, 2, 2, 0, 0, 0, 0, 0, P) }
    }
    __syncthreads();
  }

  // Parity fixup: h1[T-1] landed at parity 0 (s=256); decoder t=0 reads
  // parity 1. Copy. (h0, h2 already at parity 1.)
  {
    unsigned* dst = (unsigned*)&hb[1][1][0][0];
    const unsigned* src = (const unsigned*)&hb[0][1][0][0];
    for (int i = tid; i < 16 * 72 / 2; i += 512) dst[i] = src[i];
  }
  __syncthreads();

  // ---- decoder weights (rebuild; slot 5 = y-columns of dWih0) ----
  BUILD(0, dWhh0) BUILD(1, dWih1) BUILD(2, dWhh1) BUILD(3, dWih2) BUILD(4, dWhh2)
  BUILDU(5, dWih0)
  xwc_sel = (v4f){dWih0[U_sel * 65], dWih0[(64 + U_sel) * 65],
                  dWih0[(128 + U_sel) * 65], dWih0[(192 + U_sel) * 65]};
  fcw_sel = fcW[U_sel];

#define ACLR2                                                                 \
  v4f acc[2];                                                                 \
  acc[0] = ZV4; acc[1] = ZV4;

#define DSTEP(TP)                                                             \
  { ACLR2 LDBP(ya, 3, (TP) ^ 1) LDBP(n0, 0, (TP) ^ 1)                         \
    MATX(acc, 5, ya) MATX(acc, 0, n0)                                         \
    GUPDX(acc, 0, 3, 1, 1, t, 0, 0, TP) }                                     \
  __syncthreads();                                                            \
  { ACLR2 LDBP(n1, 0, TP) LDBP(n2, 1, (TP) ^ 1)                               \
    MATX(acc, 1, n1) MATX(acc, 2, n2)                                         \
    GUPDX(acc, 1, 4, 0, 0, t, 0, 0, TP) }                                     \
  __syncthreads();                                                            \
  { ACLR2 LDBP(n3, 1, TP) LDBP(n4, 2, (TP) ^ 1)                               \
    MATX(acc, 3, n3) MATX(acc, 4, n4)                                         \
    GUPDX(acc, 2, 5, 0, 0, t, 1, 1, TP) }                                     \
  __syncthreads();

  // ---------------- Decoder (3 serial phases/t; y-feedback) ----------------
#pragma clang loop unroll(disable)
  for (int t2 = 0; t2 < T; t2 += 2) {
    {
      const int t = t2;
      if (t > 0 && (t & 31) == 0 && tid < 128) {  // flush preds t-32..t-1
        const int ti = tid >> 2, c4 = tid & 3;
        float s = fcb0;
#pragma unroll
        for (int ww = 0; ww < 8; ++ww) s += fcring[ti][ww][c4];
        out[(b0 + c4) * T + (t - 32) + ti] = s;
      }
      DSTEP(0)
    }
    { const int t = t2 + 1; DSTEP(1) }
  }
  // final flush: t = 224..255
  if (tid < 128) {
    const int ti = tid >> 2, c4 = tid & 3;
    float s = fcb0;
#pragma unroll
    for (int ww = 0; ww < 8; ++ww) s += fcring[ti][ww][c4];
    out[(b0 + c4) * T + 224 + ti] = s;
  }

#undef DSTEP
#undef ACLR2
#undef GUPDX
#undef MATX
#undef DUO2
#undef LDBP
#undef ZV4
#undef BUILDU
#undef BUILD
}

}  // namespace

extern "C" void kernel_launch(void* const* d_in, const int* in_sizes, int n_in,
                              void* d_out, int out_size, void* d_ws, size_t ws_size,
                              hipStream_t stream) {
  const float* enc_x = (const float*)d_in[0];
  const float* dec_x = (const float*)d_in[1];
  const float* eWih0 = (const float*)d_in[2];
  const float* eWhh0 = (const float*)d_in[3];
  const float* eb0   = (const float*)d_in[4];
  const float* eWih1 = (const float*)d_in[5];
  const float* eWhh1 = (const float*)d_in[6];
  const float* eb1   = (const float*)d_in[7];
  const float* eWih2 = (const float*)d_in[8];
  const float* eWhh2 = (const float*)d_in[9];
  const float* eb2   = (const float*)d_in[10];
  const float* dWih0 = (const float*)d_in[11];
  const float* dWhh0 = (const float*)d_in[12];
  const float* db0   = (const float*)d_in[13];
  const float* dWih1 = (const float*)d_in[14];
  const float* dWhh1 = (const float*)d_in[15];
  const float* db1   = (const float*)d_in[16];
  const float* dWih2 = (const float*)d_in[17];
  const float* dWhh2 = (const float*)d_in[18];
  const float* db2   = (const float*)d_in[19];
  const float* fcW   = (const float*)d_in[20];
  const float* fcb   = (const float*)d_in[21];
  float* out = (float*)d_out;

  seq2seq_kernel<<<dim3(256), dim3(512), 0, stream>>>(
      enc_x, dec_x, eWih0, eWhh0, eb0, eWih1, eWhh1, eb1, eWih2, eWhh2, eb2,
      dWih0, dWhh0, db0, dWih1, dWhh1, db1, dWih2, dWhh2, db2, fcW, fcb, out);
}